// Round 4
// baseline (614.583 us; speedup 1.0000x reference)
//
#include <hip/hip_runtime.h>
#include <cfloat>
#include <stdint.h>

// KmeansVectorQuantizer: B=8, T=2048, G=8, D=64, V=1024
// Outputs (flat f32): ids[B*T*G], quantized_st[B*T*G*D], kmeans, commit, total
#define G_ 8
#define D_ 64
#define V_ 1024
#define BT_ 16384
#define NV_ 8                 // codebook splits (grid.z) for TLP
#define ROWS_ (V_ / NV_)      // 128 rows per split
#define TPB_ 256

typedef unsigned long long u64;
typedef uint32_t u32;

// ws layout (bytes):
//   [0..3]      float loss_sum
//   [8..11]     int   cnt_active
//   [12..15]    int   cnt_pad
//   [256)       float csqT[G_*V_]    32 KB   (transposed: [g][v], contiguous in v)
//   [33024)     int   list[BT_]      64 KB
//   [98560)     int   plist[BT_]     64 KB
//   [163072)    u64   cand[BT_*G_]    1 MB   (init 0xFF = u64 max)

__global__ void csq_kernel(const float* __restrict__ cb, float* __restrict__ csqT) {
    int idx = blockIdx.x * blockDim.x + threadIdx.x;   // flat (v*G+g)
    if (idx >= V_ * G_) return;
    const float4* r = (const float4*)(cb + (size_t)idx * D_);
    float s = 0.f;
#pragma unroll
    for (int i = 0; i < D_ / 4; ++i) {
        float4 c = r[i];
        s += c.x * c.x + c.y * c.y + c.z * c.z + c.w * c.w;
    }
    int v = idx >> 3, g = idx & (G_ - 1);
    csqT[g * V_ + v] = s;
}

// One thread per token: partition tokens into active / padded lists.
__global__ void prep_kernel(const int* __restrict__ pad,
                            int* __restrict__ cnt,
                            int* __restrict__ list,
                            int* __restrict__ cnt2,
                            int* __restrict__ plist) {
    int tok = blockIdx.x * blockDim.x + threadIdx.x;
    if (tok >= BT_) return;
    if (pad[tok] == 0) {
        int pos = atomicAdd(cnt, 1);       // wave-coalesced by compiler
        list[pos] = tok;
    } else {
        int pos = atomicAdd(cnt2, 1);
        plist[pos] = tok;
    }
}

// One wave per padded token: coalesced zero-fill of q row, ids = -1.
__global__ void pad_fill(const int* __restrict__ cnt2,
                         const int* __restrict__ plist,
                         float* __restrict__ out_ids,
                         float* __restrict__ out_q) {
    int wid  = (blockIdx.x * blockDim.x + threadIdx.x) >> 6;
    int lane = threadIdx.x & 63;
    if (wid >= cnt2[0]) return;            // wave-uniform exit
    int tok = plist[wid];
    float4 z = make_float4(0.f, 0.f, 0.f, 0.f);
    float4* q = (float4*)(out_q + (size_t)tok * (G_ * D_));
    q[lane] = z;
    q[lane + 64] = z;                      // 128 x float4 = 512 floats
    if (lane < G_) out_ids[(size_t)tok * G_ + lane] = -1.0f;
}

// Hot kernel: one token per lane; x resident in VGPRs; codebook rows via
// SGPR broadcast (s_load, wave-uniform address) -> v_fmac vD, sC, vX.
__global__ __launch_bounds__(TPB_, 4) void vq_scan(
    const float* __restrict__ inp,
    const float* __restrict__ cb,
    const float* __restrict__ csqT,
    const int* __restrict__ cnt,
    const int* __restrict__ list,
    u64* __restrict__ cand) {

    const int nact  = cnt[0];
    const int start = blockIdx.x * TPB_;
    if (start >= nact) return;             // uniform early-exit

    const int  tid   = threadIdx.x;
    const int  g     = blockIdx.y;         // wave-uniform
    const int  s     = blockIdx.z;         // codebook split
    const int  pos   = start + tid;
    const bool valid = (pos < nact);
    const int  tok   = list[valid ? pos : 0];

    const float4* xr = (const float4*)(inp + (size_t)tok * (G_ * D_) + g * D_);
    float4 x[16];
#pragma unroll
    for (int i = 0; i < 16; ++i) x[i] = xr[i];

    float best  = FLT_MAX;
    int   bestv = 0;
    const int v0 = s * ROWS_;
#pragma unroll 2
    for (int r = 0; r < ROWS_; ++r) {
        const int v = v0 + r;
        // force address math into SGPRs so the row loads scalarize
        const int roff = __builtin_amdgcn_readfirstlane((v * G_ + g) * D_);
        const float4* cr = (const float4*)(cb + roff);
        const float cs = csqT[__builtin_amdgcn_readfirstlane(g * V_ + v)];
        float a0 = 0.f, a1 = 0.f, a2 = 0.f, a3 = 0.f;
#pragma unroll
        for (int i = 0; i < 16; ++i) {
            float4 c = cr[i];
            a0 = fmaf(x[i].x, c.x, a0);
            a1 = fmaf(x[i].y, c.y, a1);
            a2 = fmaf(x[i].z, c.z, a2);
            a3 = fmaf(x[i].w, c.w, a3);
        }
        float dot  = (a0 + a1) + (a2 + a3);
        float dist = cs - 2.f * dot;
        if (dist < best) { best = dist; bestv = v; }   // strict '<': first-min
    }

    if (valid) {
        // sortable encode: (dist,id) -> u64; atomicMin == (min dist, then min id)
        u32 u = __float_as_uint(best);
        u = u ^ ((u >> 31) ? 0xFFFFFFFFu : 0x80000000u);
        u64 c = ((u64)u << 32) | (u32)bestv;
        atomicMin(&cand[(size_t)pos * G_ + g], c);
    }
}

// Epilogue: 8 lanes per (pos,g) pair -> coalesced 128B segments.
__global__ void vq_merge(const float* __restrict__ inp,
                         const float* __restrict__ cb,
                         const int* __restrict__ cnt,
                         const int* __restrict__ list,
                         const u64* __restrict__ cand,
                         float* __restrict__ out_ids,
                         float* __restrict__ out_q,
                         float* __restrict__ ws) {
    const int npair = cnt[0] * G_;
    const int tid   = threadIdx.x;
    const int idx   = blockIdx.x * (TPB_ / 8) + (tid >> 3);   // pair index
    const int sub   = tid & 7;
    float l = 0.f;
    if (idx < npair) {
        const int g   = idx & (G_ - 1);
        const int pos = idx >> 3;
        const int tok = list[pos];
        const int bestv = (int)(cand[idx] & 0xFFFFFFFFull);
        const float4* cr = (const float4*)(cb + ((size_t)bestv * G_ + g) * D_);
        const float4* xr = (const float4*)(inp + (size_t)tok * (G_ * D_) + g * D_);
        float4* qout = (float4*)(out_q + (size_t)tok * (G_ * D_) + g * D_);
#pragma unroll
        for (int h = 0; h < 2; ++h) {
            int i = sub + h * 8;
            float4 c = cr[i], xx = xr[i];
            float dx = c.x - xx.x, dy = c.y - xx.y;
            float dz = c.z - xx.z, dw = c.w - xx.w;
            l += dx * dx + dy * dy + dz * dz + dw * dw;
            qout[i] = c;
        }
        if (sub == 0) out_ids[(size_t)tok * G_ + g] = (float)bestv;
    }
#pragma unroll
    for (int off = 32; off > 0; off >>= 1) l += __shfl_down(l, off, 64);
    if ((tid & 63) == 0) atomicAdd(&ws[0], l);
}

__global__ void finalize_kernel(const float* __restrict__ ws,
                                const int* __restrict__ cnt,
                                float* __restrict__ out_losses) {
    float k = ws[0] / (float)cnt[0];
    out_losses[0] = k;        // kmeans_loss
    out_losses[1] = k;        // commitment_loss (numerically identical)
    out_losses[2] = 2.f * k;  // total (BETA=1)
}

extern "C" void kernel_launch(void* const* d_in, const int* in_sizes, int n_in,
                              void* d_out, int out_size, void* d_ws, size_t ws_size,
                              hipStream_t stream) {
    const float* inp = (const float*)d_in[0];   // (8,2048,512) f32
    const int*   pad = (const int*)d_in[1];     // (8,2048) i32
    const float* cb  = (const float*)d_in[2];   // (1024,8,64) f32

    float* out   = (float*)d_out;
    float* o_ids = out;                              // B*T*G
    float* o_q   = out + (size_t)BT_ * G_;           // B*T*G*D
    float* o_ls  = o_q + (size_t)BT_ * G_ * D_;      // 3 scalars

    float* ws    = (float*)d_ws;
    int*   cnt   = (int*)((char*)d_ws + 8);
    int*   cnt2  = (int*)((char*)d_ws + 12);
    float* csqT  = (float*)((char*)d_ws + 256);
    int*   list  = (int*)((char*)d_ws + 33024);
    int*   plist = (int*)((char*)d_ws + 98560);
    u64*   cand  = (u64*)((char*)d_ws + 163072);

    hipMemsetAsync(d_ws, 0, 256, stream);
    hipMemsetAsync(cand, 0xFF, (size_t)BT_ * G_ * sizeof(u64), stream);

    csq_kernel<<<dim3((V_ * G_ + 255) / 256), dim3(256), 0, stream>>>(cb, csqT);
    prep_kernel<<<dim3(BT_ / 256), dim3(256), 0, stream>>>(pad, cnt, list, cnt2, plist);
    pad_fill<<<dim3(BT_ * 64 / TPB_), dim3(TPB_), 0, stream>>>(cnt2, plist, o_ids, o_q);

    dim3 grid(BT_ / TPB_, G_, NV_);                  // worst-case tiles x g x split
    vq_scan<<<grid, dim3(TPB_), 0, stream>>>(inp, cb, csqT, cnt, list, cand);

    vq_merge<<<dim3((BT_ * G_ + (TPB_ / 8) - 1) / (TPB_ / 8)), dim3(TPB_), 0, stream>>>(
        inp, cb, cnt, list, cand, o_ids, o_q, ws);

    finalize_kernel<<<1, 1, 0, stream>>>(ws, cnt, o_ls);
}

// Round 5
// 418.662 us; speedup vs baseline: 1.4680x; 1.4680x over previous
//
#include <hip/hip_runtime.h>
#include <cfloat>
#include <stdint.h>

// KmeansVectorQuantizer: B=8, T=2048, G=8, D=64, V=1024
// Outputs (flat f32): ids[B*T*G], quantized_st[B*T*G*D], kmeans, commit, total
#define G_ 8
#define D_ 64
#define V_ 1024
#define BT_ 16384
#define NV_ 8                 // codebook splits (grid.z) for TLP
#define ROWS_ (V_ / NV_)      // 128 rows per split
#define TPB_ 256
#define NSLOT_ 128            // spread loss-accumulator slots

typedef unsigned long long u64;
typedef uint32_t u32;

// ws layout (bytes):
//   [0..511]    float part[128]      loss partial slots (memset 0)
//   [512..515]  int   cnt_active
//   [516..519]  int   cnt_pad
//   [1024)      float csqT[G_*V_]    32 KB  (transposed [g][v])
//   [33792)     int   list[BT_]      64 KB
//   [99328)     int   plist[BT_]     64 KB
//   [164864)    u64   cand[BT_*G_]    1 MB  (memset 0xFF)

// Fused: csq for idx<V_*G_, active/padded partition for tok<BT_.
__global__ void prep_csq(const float* __restrict__ cb, const int* __restrict__ pad,
                         float* __restrict__ csqT,
                         int* __restrict__ cnt, int* __restrict__ list,
                         int* __restrict__ cnt2, int* __restrict__ plist) {
    int idx = blockIdx.x * blockDim.x + threadIdx.x;
    if (idx < V_ * G_) {
        const float4* r = (const float4*)(cb + (size_t)idx * D_);
        float s = 0.f;
#pragma unroll
        for (int i = 0; i < D_ / 4; ++i) {
            float4 c = r[i];
            s += c.x * c.x + c.y * c.y + c.z * c.z + c.w * c.w;
        }
        csqT[(idx & (G_ - 1)) * V_ + (idx >> 3)] = s;
    }
    if (idx < BT_) {
        if (pad[idx] == 0) {
            int pos = atomicAdd(cnt, 1);       // wave-coalesced by compiler
            list[pos] = idx;
        } else {
            int pos = atomicAdd(cnt2, 1);
            plist[pos] = idx;
        }
    }
}

// One wave per padded token: coalesced zero-fill of q row, ids = -1.
__global__ void pad_fill(const int* __restrict__ cnt2,
                         const int* __restrict__ plist,
                         float* __restrict__ out_ids,
                         float* __restrict__ out_q) {
    int wid  = (blockIdx.x * blockDim.x + threadIdx.x) >> 6;
    int lane = threadIdx.x & 63;
    if (wid >= cnt2[0]) return;                // wave-uniform exit
    int tok = plist[wid];
    float4 z = make_float4(0.f, 0.f, 0.f, 0.f);
    float4* q = (float4*)(out_q + (size_t)tok * (G_ * D_));
    q[lane] = z;
    q[lane + 64] = z;
    if (lane < G_) out_ids[(size_t)tok * G_ + lane] = -1.0f;
}

// Hot kernel: one token per lane; x resident in VGPRs; codebook rows via
// SGPR broadcast (s_load, wave-uniform address) -> v_fmac vD, sC, vX.
__global__ __launch_bounds__(TPB_, 4) void vq_scan(
    const float* __restrict__ inp,
    const float* __restrict__ cb,
    const float* __restrict__ csqT,
    const int* __restrict__ cnt,
    const int* __restrict__ list,
    u64* __restrict__ cand) {

    const int nact  = cnt[0];
    const int start = blockIdx.x * TPB_;
    if (start >= nact) return;                 // uniform early-exit

    const int  tid   = threadIdx.x;
    const int  g     = blockIdx.y;             // wave-uniform
    const int  s     = blockIdx.z;             // codebook split
    const int  pos   = start + tid;
    const bool valid = (pos < nact);
    const int  tok   = list[valid ? pos : 0];

    const float4* xr = (const float4*)(inp + (size_t)tok * (G_ * D_) + g * D_);
    float4 x[16];
#pragma unroll
    for (int i = 0; i < 16; ++i) x[i] = xr[i];

    float best  = FLT_MAX;
    int   bestv = 0;
    const int v0 = s * ROWS_;
#pragma unroll 2
    for (int r = 0; r < ROWS_; ++r) {
        const int v = v0 + r;
        // force address math into SGPRs so the row loads scalarize
        const int roff = __builtin_amdgcn_readfirstlane((v * G_ + g) * D_);
        const float4* cr = (const float4*)(cb + roff);
        const float cs = csqT[__builtin_amdgcn_readfirstlane(g * V_ + v)];
        float a0 = 0.f, a1 = 0.f, a2 = 0.f, a3 = 0.f;
#pragma unroll
        for (int i = 0; i < 16; ++i) {
            float4 c = cr[i];
            a0 = fmaf(x[i].x, c.x, a0);
            a1 = fmaf(x[i].y, c.y, a1);
            a2 = fmaf(x[i].z, c.z, a2);
            a3 = fmaf(x[i].w, c.w, a3);
        }
        float dot  = (a0 + a1) + (a2 + a3);
        float dist = cs - 2.f * dot;
        if (dist < best) { best = dist; bestv = v; }   // strict '<': first-min
    }

    if (valid) {
        // sortable encode: (dist,id) -> u64; atomicMin == (min dist, then min id)
        u32 u = __float_as_uint(best);
        u = u ^ ((u >> 31) ? 0xFFFFFFFFu : 0x80000000u);
        u64 c = ((u64)u << 32) | (u32)bestv;
        atomicMin(&cand[(size_t)pos * G_ + g], c);
    }
}

// Epilogue: thread per (pos,g) pair; loss atomics spread over 128 slots.
__global__ void vq_merge(const float* __restrict__ inp,
                         const float* __restrict__ cb,
                         const int* __restrict__ cnt,
                         const int* __restrict__ list,
                         const u64* __restrict__ cand,
                         float* __restrict__ out_ids,
                         float* __restrict__ out_q,
                         float* __restrict__ part) {
    const int nact = cnt[0];
    if (blockIdx.x * TPB_ >= nact) return;     // uniform exit for idle tiles
    const int tid = threadIdx.x;
    const int pos = blockIdx.x * TPB_ + tid;
    const int g   = blockIdx.y;
    float l = 0.f;
    if (pos < nact) {
        const int tok   = list[pos];
        const int bestv = (int)(cand[(size_t)pos * G_ + g] & 0xFFFFFFFFull);
        const float4* cr = (const float4*)(cb + ((size_t)bestv * G_ + g) * D_);
        const float4* xr = (const float4*)(inp + (size_t)tok * (G_ * D_) + g * D_);
        float4* qout = (float4*)(out_q + (size_t)tok * (G_ * D_) + g * D_);
#pragma unroll
        for (int i = 0; i < 16; ++i) {
            float4 c = cr[i], xx = xr[i];
            float dx = c.x - xx.x, dy = c.y - xx.y;
            float dz = c.z - xx.z, dw = c.w - xx.w;
            l += dx * dx + dy * dy + dz * dz + dw * dw;
            qout[i] = c;
        }
        out_ids[(size_t)tok * G_ + g] = (float)bestv;
    }
#pragma unroll
    for (int off = 32; off > 0; off >>= 1) l += __shfl_down(l, off, 64);
    if ((tid & 63) == 0) {
        int wid = (blockIdx.y * gridDim.x + blockIdx.x) * (TPB_ / 64) + (tid >> 6);
        atomicAdd(&part[wid & (NSLOT_ - 1)], l);
    }
}

__global__ void finalize_kernel(const float* __restrict__ part,
                                const int* __restrict__ cnt,
                                float* __restrict__ out_losses) {
    int lane = threadIdx.x;                    // one wave of 64
    float l = part[lane] + part[lane + 64];
#pragma unroll
    for (int off = 32; off > 0; off >>= 1) l += __shfl_down(l, off, 64);
    if (lane == 0) {
        float k = l / (float)cnt[0];
        out_losses[0] = k;        // kmeans_loss
        out_losses[1] = k;        // commitment_loss (numerically identical)
        out_losses[2] = 2.f * k;  // total (BETA=1)
    }
}

extern "C" void kernel_launch(void* const* d_in, const int* in_sizes, int n_in,
                              void* d_out, int out_size, void* d_ws, size_t ws_size,
                              hipStream_t stream) {
    const float* inp = (const float*)d_in[0];   // (8,2048,512) f32
    const int*   pad = (const int*)d_in[1];     // (8,2048) i32
    const float* cb  = (const float*)d_in[2];   // (1024,8,64) f32

    float* out   = (float*)d_out;
    float* o_ids = out;                              // B*T*G
    float* o_q   = out + (size_t)BT_ * G_;           // B*T*G*D
    float* o_ls  = o_q + (size_t)BT_ * G_ * D_;      // 3 scalars

    float* part  = (float*)d_ws;
    int*   cnt   = (int*)((char*)d_ws + 512);
    int*   cnt2  = (int*)((char*)d_ws + 516);
    float* csqT  = (float*)((char*)d_ws + 1024);
    int*   list  = (int*)((char*)d_ws + 33792);
    int*   plist = (int*)((char*)d_ws + 99328);
    u64*   cand  = (u64*)((char*)d_ws + 164864);

    hipMemsetAsync(d_ws, 0, 1024, stream);
    hipMemsetAsync(cand, 0xFF, (size_t)BT_ * G_ * sizeof(u64), stream);

    prep_csq<<<dim3(BT_ / TPB_), dim3(TPB_), 0, stream>>>(cb, pad, csqT, cnt, list, cnt2, plist);
    pad_fill<<<dim3(BT_ * 64 / TPB_), dim3(TPB_), 0, stream>>>(cnt2, plist, o_ids, o_q);

    dim3 grid(BT_ / TPB_, G_, NV_);                  // worst-case tiles x g x split
    vq_scan<<<grid, dim3(TPB_), 0, stream>>>(inp, cb, csqT, cnt, list, cand);

    vq_merge<<<dim3(BT_ / TPB_, G_), dim3(TPB_), 0, stream>>>(
        inp, cb, cnt, list, cand, o_ids, o_q, part);

    finalize_kernel<<<1, dim3(64), 0, stream>>>(part, cnt, o_ls);
}

// Round 6
// 409.810 us; speedup vs baseline: 1.4997x; 1.0216x over previous
//
#include <hip/hip_runtime.h>
#include <cfloat>
#include <stdint.h>

// KmeansVectorQuantizer: B=8, T=2048, G=8, D=64, V=1024
// Outputs (flat f32): ids[B*T*G], quantized_st[B*T*G*D], kmeans, commit, total
#define G_ 8
#define D_ 64
#define V_ 1024
#define BT_ 16384
#define NV_ 8                 // codebook splits (grid.z) for TLP
#define ROWS_ (V_ / NV_)      // 128 rows per split
#define TPB_ 256
#define NSLOT_ 128            // spread loss-accumulator slots

typedef unsigned long long u64;
typedef uint32_t u32;

// ws layout (bytes):
//   [0..511]    float part[128]      loss partial slots (memset 0)
//   [512..515]  int   cnt_active
//   [516..519]  int   cnt_pad
//   [1024)      float csqT[G_*V_]    32 KB  (transposed [g][v])
//   [33792)     int   list[BT_]      64 KB
//   [99328)     int   plist[BT_]     64 KB
//   [164864)    u64   cand[BT_*G_]    1 MB  (memset 0xFF)

// Fused: csq for idx<V_*G_, active/padded partition for tok<BT_.
__global__ void prep_csq(const float* __restrict__ cb, const int* __restrict__ pad,
                         float* __restrict__ csqT,
                         int* __restrict__ cnt, int* __restrict__ list,
                         int* __restrict__ cnt2, int* __restrict__ plist) {
    int idx = blockIdx.x * blockDim.x + threadIdx.x;
    if (idx < V_ * G_) {
        const float4* r = (const float4*)(cb + (size_t)idx * D_);
        float s = 0.f;
#pragma unroll
        for (int i = 0; i < D_ / 4; ++i) {
            float4 c = r[i];
            s += c.x * c.x + c.y * c.y + c.z * c.z + c.w * c.w;
        }
        csqT[(idx & (G_ - 1)) * V_ + (idx >> 3)] = s;
    }
    if (idx < BT_) {
        if (pad[idx] == 0) {
            int pos = atomicAdd(cnt, 1);       // wave-coalesced by compiler
            list[pos] = idx;
        } else {
            int pos = atomicAdd(cnt2, 1);
            plist[pos] = idx;
        }
    }
}

// One wave per padded token: coalesced zero-fill of q row, ids = -1.
__global__ void pad_fill(const int* __restrict__ cnt2,
                         const int* __restrict__ plist,
                         float* __restrict__ out_ids,
                         float* __restrict__ out_q) {
    int wid  = (blockIdx.x * blockDim.x + threadIdx.x) >> 6;
    int lane = threadIdx.x & 63;
    if (wid >= cnt2[0]) return;                // wave-uniform exit
    int tok = plist[wid];
    float4 z = make_float4(0.f, 0.f, 0.f, 0.f);
    float4* q = (float4*)(out_q + (size_t)tok * (G_ * D_));
    q[lane] = z;
    q[lane + 64] = z;
    if (lane < G_) out_ids[(size_t)tok * G_ + lane] = -1.0f;
}

// Hot kernel: one token per lane; x PINNED in VGPRs (asm residency trick);
// codebook rows via SGPR broadcast (s_load, wave-uniform) -> v_fmac vD,sC,vX.
__global__ __launch_bounds__(TPB_, 4) void vq_scan(
    const float* __restrict__ inp,
    const float* __restrict__ cb,
    const float* __restrict__ csqT,
    const int* __restrict__ cnt,
    const int* __restrict__ list,
    u64* __restrict__ cand) {

    const int nact  = cnt[0];
    const int start = blockIdx.x * TPB_;
    if (start >= nact) return;                 // uniform early-exit

    const int  tid   = threadIdx.x;
    const int  g     = blockIdx.y;             // wave-uniform
    const int  s     = blockIdx.z;             // codebook split
    const int  pos   = start + tid;
    const bool valid = (pos < nact);
    const int  tok   = list[valid ? pos : 0];

    const float4* xr = (const float4*)(inp + (size_t)tok * (G_ * D_) + g * D_);
    float4 x[16];
#pragma unroll
    for (int i = 0; i < 16; ++i) x[i] = xr[i];
    // Pin x in VGPRs: opaque asm outputs cannot be rematerialized from memory,
    // so the allocator must keep all 64 floats register-resident for the scan.
#pragma unroll
    for (int i = 0; i < 16; ++i) {
        asm volatile("" : "+v"(x[i].x), "+v"(x[i].y), "+v"(x[i].z), "+v"(x[i].w));
    }

    float best  = FLT_MAX;
    int   bestv = 0;
    const int v0 = s * ROWS_;
#pragma unroll 2
    for (int r = 0; r < ROWS_; ++r) {
        const int v = v0 + r;
        // force address math into SGPRs so the row loads scalarize
        const int roff = __builtin_amdgcn_readfirstlane((v * G_ + g) * D_);
        const float4* cr = (const float4*)(cb + roff);
        const float cs = csqT[__builtin_amdgcn_readfirstlane(g * V_ + v)];
        float a0 = 0.f, a1 = 0.f, a2 = 0.f, a3 = 0.f;
#pragma unroll
        for (int i = 0; i < 16; ++i) {
            float4 c = cr[i];
            a0 = fmaf(x[i].x, c.x, a0);
            a1 = fmaf(x[i].y, c.y, a1);
            a2 = fmaf(x[i].z, c.z, a2);
            a3 = fmaf(x[i].w, c.w, a3);
        }
        float dot  = (a0 + a1) + (a2 + a3);
        float dist = cs - 2.f * dot;
        if (dist < best) { best = dist; bestv = v; }   // strict '<': first-min
    }

    if (valid) {
        // sortable encode: (dist,id) -> u64; atomicMin == (min dist, then min id)
        u32 u = __float_as_uint(best);
        u = u ^ ((u >> 31) ? 0xFFFFFFFFu : 0x80000000u);
        u64 c = ((u64)u << 32) | (u32)bestv;
        atomicMin(&cand[(size_t)pos * G_ + g], c);
    }
}

// Epilogue: thread per (pos,g) pair; loss atomics spread over 128 slots.
__global__ void vq_merge(const float* __restrict__ inp,
                         const float* __restrict__ cb,
                         const int* __restrict__ cnt,
                         const int* __restrict__ list,
                         const u64* __restrict__ cand,
                         float* __restrict__ out_ids,
                         float* __restrict__ out_q,
                         float* __restrict__ part) {
    const int nact = cnt[0];
    if (blockIdx.x * TPB_ >= nact) return;     // uniform exit for idle tiles
    const int tid = threadIdx.x;
    const int pos = blockIdx.x * TPB_ + tid;
    const int g   = blockIdx.y;
    float l = 0.f;
    if (pos < nact) {
        const int tok   = list[pos];
        const int bestv = (int)(cand[(size_t)pos * G_ + g] & 0xFFFFFFFFull);
        const float4* cr = (const float4*)(cb + ((size_t)bestv * G_ + g) * D_);
        const float4* xr = (const float4*)(inp + (size_t)tok * (G_ * D_) + g * D_);
        float4* qout = (float4*)(out_q + (size_t)tok * (G_ * D_) + g * D_);
#pragma unroll
        for (int i = 0; i < 16; ++i) {
            float4 c = cr[i], xx = xr[i];
            float dx = c.x - xx.x, dy = c.y - xx.y;
            float dz = c.z - xx.z, dw = c.w - xx.w;
            l += dx * dx + dy * dy + dz * dz + dw * dw;
            qout[i] = c;
        }
        out_ids[(size_t)tok * G_ + g] = (float)bestv;
    }
#pragma unroll
    for (int off = 32; off > 0; off >>= 1) l += __shfl_down(l, off, 64);
    if ((tid & 63) == 0) {
        int wid = (blockIdx.y * gridDim.x + blockIdx.x) * (TPB_ / 64) + (tid >> 6);
        atomicAdd(&part[wid & (NSLOT_ - 1)], l);
    }
}

__global__ void finalize_kernel(const float* __restrict__ part,
                                const int* __restrict__ cnt,
                                float* __restrict__ out_losses) {
    int lane = threadIdx.x;                    // one wave of 64
    float l = part[lane] + part[lane + 64];
#pragma unroll
    for (int off = 32; off > 0; off >>= 1) l += __shfl_down(l, off, 64);
    if (lane == 0) {
        float k = l / (float)cnt[0];
        out_losses[0] = k;        // kmeans_loss
        out_losses[1] = k;        // commitment_loss (numerically identical)
        out_losses[2] = 2.f * k;  // total (BETA=1)
    }
}

extern "C" void kernel_launch(void* const* d_in, const int* in_sizes, int n_in,
                              void* d_out, int out_size, void* d_ws, size_t ws_size,
                              hipStream_t stream) {
    const float* inp = (const float*)d_in[0];   // (8,2048,512) f32
    const int*   pad = (const int*)d_in[1];     // (8,2048) i32
    const float* cb  = (const float*)d_in[2];   // (1024,8,64) f32

    float* out   = (float*)d_out;
    float* o_ids = out;                              // B*T*G
    float* o_q   = out + (size_t)BT_ * G_;           // B*T*G*D
    float* o_ls  = o_q + (size_t)BT_ * G_ * D_;      // 3 scalars

    float* part  = (float*)d_ws;
    int*   cnt   = (int*)((char*)d_ws + 512);
    int*   cnt2  = (int*)((char*)d_ws + 516);
    float* csqT  = (float*)((char*)d_ws + 1024);
    int*   list  = (int*)((char*)d_ws + 33792);
    int*   plist = (int*)((char*)d_ws + 99328);
    u64*   cand  = (u64*)((char*)d_ws + 164864);

    hipMemsetAsync(d_ws, 0, 1024, stream);
    hipMemsetAsync(cand, 0xFF, (size_t)BT_ * G_ * sizeof(u64), stream);

    prep_csq<<<dim3(BT_ / TPB_), dim3(TPB_), 0, stream>>>(cb, pad, csqT, cnt, list, cnt2, plist);
    pad_fill<<<dim3(BT_ * 64 / TPB_), dim3(TPB_), 0, stream>>>(cnt2, plist, o_ids, o_q);

    dim3 grid(BT_ / TPB_, G_, NV_);                  // worst-case tiles x g x split
    vq_scan<<<grid, dim3(TPB_), 0, stream>>>(inp, cb, csqT, cnt, list, cand);

    vq_merge<<<dim3(BT_ / TPB_, G_), dim3(TPB_), 0, stream>>>(
        inp, cb, cnt, list, cand, o_ids, o_q, part);

    finalize_kernel<<<1, dim3(64), 0, stream>>>(part, cnt, o_ls);
}

// Round 7
// 327.108 us; speedup vs baseline: 1.8788x; 1.2528x over previous
//
#include <hip/hip_runtime.h>
#include <cfloat>
#include <stdint.h>

// KmeansVectorQuantizer: B=8, T=2048, G=8, D=64, V=1024
// Outputs (flat f32): ids[B*T*G], quantized_st[B*T*G*D], kmeans, commit, total
#define G_ 8
#define D_ 64
#define V_ 1024
#define BT_ 16384
#define TPB_ 256
#define NSLOT_ 128            // spread loss-accumulator slots
#define CW_CHUNK_ 256         // codewords staged per LDS chunk (4 chunks)
#define DH_ 32                // d-half staged per CT refill

typedef unsigned long long u64;
typedef uint32_t u32;

// ws layout (bytes):
//   [0..511]    float part[128]      loss partial slots (memset 0)
//   [512..515]  int   cnt_active
//   [516..519]  int   cnt_pad
//   [1024)      float csqT[G_*V_]    32 KB  (transposed [g][v])
//   [33792)     int   list[BT_]      64 KB
//   [99328)     int   plist[BT_]     64 KB

// Fused: csq for idx<V_*G_, active/padded partition for tok<BT_.
__global__ void prep_csq(const float* __restrict__ cb, const int* __restrict__ pad,
                         float* __restrict__ csqT,
                         int* __restrict__ cnt, int* __restrict__ list,
                         int* __restrict__ cnt2, int* __restrict__ plist) {
    int idx = blockIdx.x * blockDim.x + threadIdx.x;
    if (idx < V_ * G_) {
        const float4* r = (const float4*)(cb + (size_t)idx * D_);
        float s = 0.f;
#pragma unroll
        for (int i = 0; i < D_ / 4; ++i) {
            float4 c = r[i];
            s += c.x * c.x + c.y * c.y + c.z * c.z + c.w * c.w;
        }
        csqT[(idx & (G_ - 1)) * V_ + (idx >> 3)] = s;
    }
    if (idx < BT_) {
        if (pad[idx] == 0) {
            int pos = atomicAdd(cnt, 1);       // wave-coalesced by compiler
            list[pos] = idx;
        } else {
            int pos = atomicAdd(cnt2, 1);
            plist[pos] = idx;
        }
    }
}

// One wave per padded token: coalesced zero-fill of q row, ids = -1.
__global__ void pad_fill(const int* __restrict__ cnt2,
                         const int* __restrict__ plist,
                         float* __restrict__ out_ids,
                         float* __restrict__ out_q) {
    int wid  = (blockIdx.x * blockDim.x + threadIdx.x) >> 6;
    int lane = threadIdx.x & 63;
    if (wid >= cnt2[0]) return;                // wave-uniform exit
    int tok = plist[wid];
    float4 z = make_float4(0.f, 0.f, 0.f, 0.f);
    float4* q = (float4*)(out_q + (size_t)tok * (G_ * D_));
    q[lane] = z;
    q[lane + 64] = z;
    if (lane < G_) out_ids[(size_t)tok * G_ + lane] = -1.0f;
}

// Register-blocked tile kernel: block = 64 tokens x 256 codewords per chunk,
// thread = 8x8 accumulators. X^T and C^T staged in LDS; 4 ds_read_b128 feed
// 64 v_fmac per d-step (8x operand reuse vs rounds 2-6). Argmin finalized
// in-block; ids/q/loss epilogue fused (cand/merge kernels eliminated).
__global__ __launch_bounds__(TPB_, 3) void vq_scan(
    const float* __restrict__ inp,
    const float* __restrict__ cb,
    const float* __restrict__ csqT,
    const int* __restrict__ cnt,
    const int* __restrict__ list,
    float* __restrict__ out_ids,
    float* __restrict__ out_q,
    float* __restrict__ part) {

    __shared__ __align__(16) float XT[64 * 64];          // [d][tok]   16 KB
    __shared__ __align__(16) float CT[DH_ * CW_CHUNK_];  // [dl][cw]   32 KB
    __shared__ float csq_s[CW_CHUNK_];                   //             1 KB
    __shared__ u64 merge_s[4 * 64];                      //             2 KB
    __shared__ u64 win_s[64];                            //           0.5 KB

    const int nact = cnt[0];
    const int tile = blockIdx.x;
    if (tile * 64 >= nact) return;             // uniform early-exit
    const int g   = blockIdx.y;
    const int tid = threadIdx.x;

    // ---- stage X^T [d][tok] (once) ----
    {
        int tl = tid >> 2, dq = tid & 3;
        int p  = tile * 64 + tl;
        int tok = list[p < nact ? p : 0];
        const float4* xr = (const float4*)(inp + (size_t)tok * (G_ * D_) + g * D_) + dq * 4;
#pragma unroll
        for (int k = 0; k < 4; ++k) {
            float4 v = xr[k];
            int d = dq * 16 + k * 4;
            XT[(d + 0) * 64 + tl] = v.x;
            XT[(d + 1) * 64 + tl] = v.y;
            XT[(d + 2) * 64 + tl] = v.z;
            XT[(d + 3) * 64 + tl] = v.w;
        }
    }

    const int tg = tid & 7;        // token group: tokens tg*8..tg*8+7
    const int cg = tid >> 3;       // cw group 0..31: cws cg*8..cg*8+7 (per chunk)

    float bestd[8];
    int   bestid[8];
#pragma unroll
    for (int i = 0; i < 8; ++i) { bestd[i] = FLT_MAX; bestid[i] = 0; }

    for (int step = 0; step < 4; ++step) {
        const int cw0 = step * CW_CHUNK_;
        csq_s[tid] = csqT[g * V_ + cw0 + tid];

        float acc[8][8];
#pragma unroll
        for (int i = 0; i < 8; ++i)
#pragma unroll
            for (int j = 0; j < 8; ++j) acc[i][j] = 0.f;

        for (int h = 0; h < 2; ++h) {
            __syncthreads();   // CT reuse guard (also covers XT/csq_s writes)
            // ---- stage C^T [dl][cw]: thread = one codebook row, one d-half ----
            {
                const float4* crow =
                    (const float4*)(cb + ((size_t)(cw0 + tid) * G_ + g) * D_ + h * DH_);
#pragma unroll
                for (int k = 0; k < 8; ++k) {
                    float4 v = crow[k];
                    int dl = k * 4;
                    CT[(dl + 0) * CW_CHUNK_ + tid] = v.x;
                    CT[(dl + 1) * CW_CHUNK_ + tid] = v.y;
                    CT[(dl + 2) * CW_CHUNK_ + tid] = v.z;
                    CT[(dl + 3) * CW_CHUNK_ + tid] = v.w;
                }
            }
            __syncthreads();

#pragma unroll 4
            for (int dl = 0; dl < DH_; ++dl) {
                const int d = h * DH_ + dl;
                float4 xa = *(const float4*)&XT[d * 64 + tg * 8];
                float4 xb = *(const float4*)&XT[d * 64 + tg * 8 + 4];
                float4 ca = *(const float4*)&CT[dl * CW_CHUNK_ + cg * 8];
                float4 cb4 = *(const float4*)&CT[dl * CW_CHUNK_ + cg * 8 + 4];
                float xs[8] = {xa.x, xa.y, xa.z, xa.w, xb.x, xb.y, xb.z, xb.w};
                float cs[8] = {ca.x, ca.y, ca.z, ca.w, cb4.x, cb4.y, cb4.z, cb4.w};
#pragma unroll
                for (int i = 0; i < 8; ++i)
#pragma unroll
                    for (int j = 0; j < 8; ++j)
                        acc[i][j] = fmaf(xs[i], cs[j], acc[i][j]);
            }
        }

        // ---- fold chunk into running argmin ----
#pragma unroll
        for (int j = 0; j < 8; ++j) {
            float cq = csq_s[cg * 8 + j];
            int   v  = cw0 + cg * 8 + j;
#pragma unroll
            for (int i = 0; i < 8; ++i) {
                float dist = cq - 2.f * acc[i][j];
                if (dist < bestd[i]) { bestd[i] = dist; bestid[i] = v; }  // first-min
            }
        }
        __syncthreads();   // protect csq_s before next step's overwrite
    }

    // ---- cross-lane / cross-wave argmin merge ----
    const int lane = tid & 63;
    const int w    = tid >> 6;
    u64 pk[8];
#pragma unroll
    for (int i = 0; i < 8; ++i) {
        u32 u = __float_as_uint(bestd[i]);
        u = u ^ ((u >> 31) ? 0xFFFFFFFFu : 0x80000000u);   // sortable float
        pk[i] = ((u64)u << 32) | (u32)bestid[i];           // (dist, id) packed
    }
#pragma unroll
    for (int off = 8; off <= 32; off <<= 1) {
#pragma unroll
        for (int i = 0; i < 8; ++i) {
            u64 o = __shfl_xor(pk[i], off, 64);
            pk[i] = (o < pk[i]) ? o : pk[i];
        }
    }
    if (lane < 8) {        // one lane per token-group per wave
#pragma unroll
        for (int i = 0; i < 8; ++i) merge_s[w * 64 + lane * 8 + i] = pk[i];
    }
    __syncthreads();
    if (tid < 64) {
        u64 q = merge_s[tid];
#pragma unroll
        for (int ww = 1; ww < 4; ++ww) {
            u64 o = merge_s[ww * 64 + tid];
            q = (o < q) ? o : q;
        }
        win_s[tid] = q;
    }
    __syncthreads();

    // ---- fused epilogue: ids, quantized, loss ----
    float l = 0.f;
    {
        int tl = tid >> 2, qv = tid & 3;
        int p  = tile * 64 + tl;
        if (p < nact) {
            int tok = list[p];
            int id  = (int)(win_s[tl] & 0xFFFFFFFFull);
            const float4* cr = (const float4*)(cb + ((size_t)id * G_ + g) * D_) + qv * 4;
            const float4* xr = (const float4*)(inp + (size_t)tok * (G_ * D_) + g * D_) + qv * 4;
            float4* qo = (float4*)(out_q + (size_t)tok * (G_ * D_) + g * D_) + qv * 4;
#pragma unroll
            for (int k = 0; k < 4; ++k) {
                float4 c = cr[k], xx = xr[k];
                float dx = c.x - xx.x, dy = c.y - xx.y;
                float dz = c.z - xx.z, dw = c.w - xx.w;
                l += dx * dx + dy * dy + dz * dz + dw * dw;
                qo[k] = c;
            }
            if (qv == 0) out_ids[(size_t)tok * G_ + g] = (float)id;
        }
    }
#pragma unroll
    for (int off = 32; off > 0; off >>= 1) l += __shfl_down(l, off, 64);
    if (lane == 0) {
        int slot = ((blockIdx.y * gridDim.x + blockIdx.x) * 4 + w) & (NSLOT_ - 1);
        atomicAdd(&part[slot], l);
    }
}

__global__ void finalize_kernel(const float* __restrict__ part,
                                const int* __restrict__ cnt,
                                float* __restrict__ out_losses) {
    int lane = threadIdx.x;                    // one wave of 64
    float l = part[lane] + part[lane + 64];
#pragma unroll
    for (int off = 32; off > 0; off >>= 1) l += __shfl_down(l, off, 64);
    if (lane == 0) {
        float k = l / (float)cnt[0];
        out_losses[0] = k;        // kmeans_loss
        out_losses[1] = k;        // commitment_loss (numerically identical)
        out_losses[2] = 2.f * k;  // total (BETA=1)
    }
}

extern "C" void kernel_launch(void* const* d_in, const int* in_sizes, int n_in,
                              void* d_out, int out_size, void* d_ws, size_t ws_size,
                              hipStream_t stream) {
    const float* inp = (const float*)d_in[0];   // (8,2048,512) f32
    const int*   pad = (const int*)d_in[1];     // (8,2048) i32
    const float* cb  = (const float*)d_in[2];   // (1024,8,64) f32

    float* out   = (float*)d_out;
    float* o_ids = out;                              // B*T*G
    float* o_q   = out + (size_t)BT_ * G_;           // B*T*G*D
    float* o_ls  = o_q + (size_t)BT_ * G_ * D_;      // 3 scalars

    float* part  = (float*)d_ws;
    int*   cnt   = (int*)((char*)d_ws + 512);
    int*   cnt2  = (int*)((char*)d_ws + 516);
    float* csqT  = (float*)((char*)d_ws + 1024);
    int*   list  = (int*)((char*)d_ws + 33792);
    int*   plist = (int*)((char*)d_ws + 99328);

    hipMemsetAsync(d_ws, 0, 1024, stream);

    prep_csq<<<dim3(BT_ / TPB_), dim3(TPB_), 0, stream>>>(cb, pad, csqT, cnt, list, cnt2, plist);
    pad_fill<<<dim3(BT_ * 64 / TPB_), dim3(TPB_), 0, stream>>>(cnt2, plist, o_ids, o_q);

    dim3 grid(BT_ / 64, G_);                   // worst-case 64-token tiles x g
    vq_scan<<<grid, dim3(TPB_), 0, stream>>>(inp, cb, csqT, cnt, list, o_ids, o_q, part);

    finalize_kernel<<<1, dim3(64), 0, stream>>>(part, cnt, o_ls);
}

// Round 8
// 203.627 us; speedup vs baseline: 3.0182x; 1.6064x over previous
//
#include <hip/hip_runtime.h>
#include <cfloat>
#include <stdint.h>

// KmeansVectorQuantizer: B=8, T=2048, G=8, D=64, V=1024
// Outputs (flat f32): ids[B*T*G], quantized_st[B*T*G*D], kmeans, commit, total
#define G_ 8
#define D_ 64
#define V_ 1024
#define BT_ 16384
#define TPB_ 256
#define NSLOT_ 128            // spread loss-accumulator slots
#define CW_CHUNK_ 512         // codewords staged per LDS chunk (2 chunks)
#define DH_ 16                // d-slice staged per CT refill (4 refills/chunk)

typedef unsigned long long u64;
typedef uint32_t u32;

// ws layout (bytes):
//   [0..511]    float part[128]      loss partial slots (memset 0)
//   [512..515]  int   cnt_active
//   [516..519]  int   cnt_pad
//   [1024)      float csqT[G_*V_]    32 KB  (transposed [g][v])
//   [33792)     int   list[BT_]      64 KB
//   [99328)     int   plist[BT_]     64 KB

// Fused: csq for idx<V_*G_; block-aggregated compaction (2 atomics per block,
// not per thread -- per-thread return-value atomics cost ~13ns each and were
// ~130us/call in rounds 4-7).
__global__ void prep_csq(const float* __restrict__ cb, const int* __restrict__ pad,
                         float* __restrict__ csqT,
                         int* __restrict__ cnt, int* __restrict__ list,
                         int* __restrict__ cnt2, int* __restrict__ plist) {
    const int tid = threadIdx.x;
    const int idx = blockIdx.x * TPB_ + tid;     // < BT_ (exact grid)

    if (idx < V_ * G_) {
        const float4* r = (const float4*)(cb + (size_t)idx * D_);
        float s = 0.f;
#pragma unroll
        for (int i = 0; i < D_ / 4; ++i) {
            float4 c = r[i];
            s += c.x * c.x + c.y * c.y + c.z * c.z + c.w * c.w;
        }
        csqT[(idx & (G_ - 1)) * V_ + (idx >> 3)] = s;
    }

    __shared__ int s_cnt[8];      // [0..3] active per wave, [4..7] padded
    __shared__ int s_base[2];
    const int lane = tid & 63, w = tid >> 6;
    const bool active = (pad[idx] == 0);
    u64 bal = __ballot(active);
    int na  = __popcll(bal);
    if (lane == 0) { s_cnt[w] = na; s_cnt[4 + w] = 64 - na; }
    __syncthreads();
    if (tid == 0) {
        int ta = s_cnt[0] + s_cnt[1] + s_cnt[2] + s_cnt[3];
        s_base[0] = atomicAdd(cnt, ta);
        s_base[1] = atomicAdd(cnt2, TPB_ - ta);
    }
    __syncthreads();
    int pre_a = 0, pre_p = 0;
    for (int i = 0; i < w; ++i) { pre_a += s_cnt[i]; pre_p += s_cnt[4 + i]; }
    const u64 mb = ((u64)1 << lane) - 1;
    if (active) list[s_base[0] + pre_a + __popcll(bal & mb)]  = idx;
    else        plist[s_base[1] + pre_p + __popcll(~bal & mb)] = idx;
}

// One wave per padded token: coalesced zero-fill of q row, ids = -1.
__global__ void pad_fill(const int* __restrict__ cnt2,
                         const int* __restrict__ plist,
                         float* __restrict__ out_ids,
                         float* __restrict__ out_q) {
    int wid  = (blockIdx.x * blockDim.x + threadIdx.x) >> 6;
    int lane = threadIdx.x & 63;
    if (wid >= cnt2[0]) return;                // wave-uniform exit
    int tok = plist[wid];
    float4 z = make_float4(0.f, 0.f, 0.f, 0.f);
    float4* q = (float4*)(out_q + (size_t)tok * (G_ * D_));
    q[lane] = z;
    q[lane + 64] = z;
    if (lane < G_) out_ids[(size_t)tok * G_ + lane] = -1.0f;
}

// Register-blocked tile kernel: 64 tokens x 512-cw chunks, thread = 8x16 acc.
// Per d-step per wave: 6 ds_read_b128 (72 cy LDS) feed 256 VALU-cy -> ~89%
// VALU ceiling at 8 waves/CU (R7's 8x8 tile: 48/128 -> 66% and measured 58%).
__global__ __launch_bounds__(TPB_, 2) void vq_scan(
    const float* __restrict__ inp,
    const float* __restrict__ cb,
    const float* __restrict__ csqT,
    const int* __restrict__ cnt,
    const int* __restrict__ list,
    float* __restrict__ out_ids,
    float* __restrict__ out_q,
    float* __restrict__ part) {

    __shared__ __align__(16) float XT[64 * 64];          // [d][tok]   16 KB
    __shared__ __align__(16) float CT[DH_ * CW_CHUNK_];  // [dl][cw]   32 KB
    __shared__ float csq_s[CW_CHUNK_];                   //             2 KB
    __shared__ u64 merge_s[4 * 64];                      //             2 KB
    __shared__ u64 win_s[64];                            //           0.5 KB

    const int nact = cnt[0];
    const int tile = blockIdx.x;
    if (tile * 64 >= nact) return;             // uniform early-exit
    const int g   = blockIdx.y;
    const int tid = threadIdx.x;

    // ---- stage X^T [d][tok] (once) ----
    {
        int tl = tid >> 2, dq = tid & 3;
        int p  = tile * 64 + tl;
        int tok = list[p < nact ? p : 0];
        const float4* xr = (const float4*)(inp + (size_t)tok * (G_ * D_) + g * D_) + dq * 4;
#pragma unroll
        for (int k = 0; k < 4; ++k) {
            float4 v = xr[k];
            int d = dq * 16 + k * 4;
            XT[(d + 0) * 64 + tl] = v.x;
            XT[(d + 1) * 64 + tl] = v.y;
            XT[(d + 2) * 64 + tl] = v.z;
            XT[(d + 3) * 64 + tl] = v.w;
        }
    }

    const int tg = tid & 7;        // token group: tokens tg*8..tg*8+7
    const int cg = tid >> 3;       // cw group 0..31: cws cg*16..+15 (per chunk)

    float bestd[8];
    int   bestid[8];
#pragma unroll
    for (int i = 0; i < 8; ++i) { bestd[i] = FLT_MAX; bestid[i] = 0; }

    for (int step = 0; step < 2; ++step) {
        const int cw0 = step * CW_CHUNK_;
        csq_s[tid]        = csqT[g * V_ + cw0 + tid];
        csq_s[tid + 256]  = csqT[g * V_ + cw0 + tid + 256];

        float acc[8][16];
#pragma unroll
        for (int i = 0; i < 8; ++i)
#pragma unroll
            for (int j = 0; j < 16; ++j) acc[i][j] = 0.f;

        for (int h = 0; h < 4; ++h) {
            __syncthreads();   // CT reuse guard (also covers XT/csq_s writes)
            // ---- stage C^T [dl][cw]: thread = 2 codebook rows, one d-slice ----
            {
                const float4* crow =
                    (const float4*)(cb + ((size_t)(cw0 + tid) * G_ + g) * D_ + h * DH_);
                const float4* crow2 =
                    (const float4*)(cb + ((size_t)(cw0 + tid + 256) * G_ + g) * D_ + h * DH_);
#pragma unroll
                for (int k = 0; k < 4; ++k) {
                    float4 v = crow[k];
                    float4 v2 = crow2[k];
                    int dl = k * 4;
                    CT[(dl + 0) * CW_CHUNK_ + tid] = v.x;
                    CT[(dl + 1) * CW_CHUNK_ + tid] = v.y;
                    CT[(dl + 2) * CW_CHUNK_ + tid] = v.z;
                    CT[(dl + 3) * CW_CHUNK_ + tid] = v.w;
                    CT[(dl + 0) * CW_CHUNK_ + tid + 256] = v2.x;
                    CT[(dl + 1) * CW_CHUNK_ + tid + 256] = v2.y;
                    CT[(dl + 2) * CW_CHUNK_ + tid + 256] = v2.z;
                    CT[(dl + 3) * CW_CHUNK_ + tid + 256] = v2.w;
                }
            }
            __syncthreads();

#pragma unroll 2
            for (int dl = 0; dl < DH_; ++dl) {
                const int d = h * DH_ + dl;
                float4 xa = *(const float4*)&XT[d * 64 + tg * 8];
                float4 xb = *(const float4*)&XT[d * 64 + tg * 8 + 4];
                float4 c0 = *(const float4*)&CT[dl * CW_CHUNK_ + cg * 16];
                float4 c1 = *(const float4*)&CT[dl * CW_CHUNK_ + cg * 16 + 4];
                float4 c2 = *(const float4*)&CT[dl * CW_CHUNK_ + cg * 16 + 8];
                float4 c3 = *(const float4*)&CT[dl * CW_CHUNK_ + cg * 16 + 12];
                float xs[8] = {xa.x, xa.y, xa.z, xa.w, xb.x, xb.y, xb.z, xb.w};
                float cs[16] = {c0.x, c0.y, c0.z, c0.w, c1.x, c1.y, c1.z, c1.w,
                                c2.x, c2.y, c2.z, c2.w, c3.x, c3.y, c3.z, c3.w};
#pragma unroll
                for (int i = 0; i < 8; ++i)
#pragma unroll
                    for (int j = 0; j < 16; ++j)
                        acc[i][j] = fmaf(xs[i], cs[j], acc[i][j]);
            }
        }

        // ---- fold chunk into running argmin ----
#pragma unroll
        for (int j = 0; j < 16; ++j) {
            float cq = csq_s[cg * 16 + j];
            int   v  = cw0 + cg * 16 + j;
#pragma unroll
            for (int i = 0; i < 8; ++i) {
                float dist = cq - 2.f * acc[i][j];
                if (dist < bestd[i]) { bestd[i] = dist; bestid[i] = v; }  // first-min
            }
        }
        __syncthreads();   // protect csq_s before next chunk's restage
    }

    // ---- cross-lane / cross-wave argmin merge ----
    const int lane = tid & 63;
    const int w    = tid >> 6;
    u64 pk[8];
#pragma unroll
    for (int i = 0; i < 8; ++i) {
        u32 u = __float_as_uint(bestd[i]);
        u = u ^ ((u >> 31) ? 0xFFFFFFFFu : 0x80000000u);   // sortable float
        pk[i] = ((u64)u << 32) | (u32)bestid[i];           // (dist, id) packed
    }
#pragma unroll
    for (int off = 8; off <= 32; off <<= 1) {
#pragma unroll
        for (int i = 0; i < 8; ++i) {
            u64 o = __shfl_xor(pk[i], off, 64);
            pk[i] = (o < pk[i]) ? o : pk[i];
        }
    }
    if (lane < 8) {        // one lane per token-group per wave
#pragma unroll
        for (int i = 0; i < 8; ++i) merge_s[w * 64 + lane * 8 + i] = pk[i];
    }
    __syncthreads();
    if (tid < 64) {
        u64 q = merge_s[tid];
#pragma unroll
        for (int ww = 1; ww < 4; ++ww) {
            u64 o = merge_s[ww * 64 + tid];
            q = (o < q) ? o : q;
        }
        win_s[tid] = q;
    }
    __syncthreads();

    // ---- fused epilogue: ids, quantized, loss ----
    float l = 0.f;
    {
        int tl = tid >> 2, qv = tid & 3;
        int p  = tile * 64 + tl;
        if (p < nact) {
            int tok = list[p];
            int id  = (int)(win_s[tl] & 0xFFFFFFFFull);
            const float4* cr = (const float4*)(cb + ((size_t)id * G_ + g) * D_) + qv * 4;
            const float4* xr = (const float4*)(inp + (size_t)tok * (G_ * D_) + g * D_) + qv * 4;
            float4* qo = (float4*)(out_q + (size_t)tok * (G_ * D_) + g * D_) + qv * 4;
#pragma unroll
            for (int k = 0; k < 4; ++k) {
                float4 c = cr[k], xx = xr[k];
                float dx = c.x - xx.x, dy = c.y - xx.y;
                float dz = c.z - xx.z, dw = c.w - xx.w;
                l += dx * dx + dy * dy + dz * dz + dw * dw;
                qo[k] = c;
            }
            if (qv == 0) out_ids[(size_t)tok * G_ + g] = (float)id;
        }
    }
#pragma unroll
    for (int off = 32; off > 0; off >>= 1) l += __shfl_down(l, off, 64);
    if (lane == 0) {
        int slot = ((blockIdx.y * gridDim.x + blockIdx.x) * 4 + w) & (NSLOT_ - 1);
        atomicAdd(&part[slot], l);
    }
}

__global__ void finalize_kernel(const float* __restrict__ part,
                                const int* __restrict__ cnt,
                                float* __restrict__ out_losses) {
    int lane = threadIdx.x;                    // one wave of 64
    float l = part[lane] + part[lane + 64];
#pragma unroll
    for (int off = 32; off > 0; off >>= 1) l += __shfl_down(l, off, 64);
    if (lane == 0) {
        float k = l / (float)cnt[0];
        out_losses[0] = k;        // kmeans_loss
        out_losses[1] = k;        // commitment_loss (numerically identical)
        out_losses[2] = 2.f * k;  // total (BETA=1)
    }
}

extern "C" void kernel_launch(void* const* d_in, const int* in_sizes, int n_in,
                              void* d_out, int out_size, void* d_ws, size_t ws_size,
                              hipStream_t stream) {
    const float* inp = (const float*)d_in[0];   // (8,2048,512) f32
    const int*   pad = (const int*)d_in[1];     // (8,2048) i32
    const float* cb  = (const float*)d_in[2];   // (1024,8,64) f32

    float* out   = (float*)d_out;
    float* o_ids = out;                              // B*T*G
    float* o_q   = out + (size_t)BT_ * G_;           // B*T*G*D
    float* o_ls  = o_q + (size_t)BT_ * G_ * D_;      // 3 scalars

    float* part  = (float*)d_ws;
    int*   cnt   = (int*)((char*)d_ws + 512);
    int*   cnt2  = (int*)((char*)d_ws + 516);
    float* csqT  = (float*)((char*)d_ws + 1024);
    int*   list  = (int*)((char*)d_ws + 33792);
    int*   plist = (int*)((char*)d_ws + 99328);

    hipMemsetAsync(d_ws, 0, 1024, stream);

    prep_csq<<<dim3(BT_ / TPB_), dim3(TPB_), 0, stream>>>(cb, pad, csqT, cnt, list, cnt2, plist);
    pad_fill<<<dim3(BT_ * 64 / TPB_), dim3(TPB_), 0, stream>>>(cnt2, plist, o_ids, o_q);

    dim3 grid(BT_ / 64, G_);                   // worst-case 64-token tiles x g
    vq_scan<<<grid, dim3(TPB_), 0, stream>>>(inp, cb, csqT, cnt, list, o_ids, o_q, part);

    finalize_kernel<<<1, dim3(64), 0, stream>>>(part, cnt, o_ls);
}

// Round 9
// 202.028 us; speedup vs baseline: 3.0421x; 1.0079x over previous
//
#include <hip/hip_runtime.h>
#include <cfloat>
#include <stdint.h>

// KmeansVectorQuantizer: B=8, T=2048, G=8, D=64, V=1024
// Outputs (flat f32): ids[B*T*G], quantized_st[B*T*G*D], kmeans, commit, total
#define G_ 8
#define D_ 64
#define V_ 1024
#define BT_ 16384
#define TPB_ 256
#define NSLOT_ 128            // spread loss-accumulator slots
#define TOKS_ 128             // tokens per scan block
#define CWC_ 256              // codewords per chunk (4 chunks)
#define DH_ 32                // d-slice per stage phase (2 phases/chunk, 8 total)
#define XROW_ 140             // staggered XT row stride (floats)

typedef unsigned long long u64;
typedef uint32_t u32;

// ws layout (bytes):
//   [0..511]    float part[128]     loss partial slots (memset 0)
//   [512..515]  int   cnt_active    (memset 0)
//   [1024)      float csqT[G_*V_]   32 KB  (transposed [g][v])
//   [33792)     int   list[BT_]     64 KB

// token-group stagger: breaks the tok-stride-8 4-way bank alias (slots 2tg+(tg>>2) mod 8)
__device__ __forceinline__ int xoff(int tg) { return tg * 8 + (tg >> 2) * 4; }

// Fused prep: csq transpose, block-aggregated active compaction (1 atomic/block),
// and in-block coalesced zero-fill of padded tokens (pad_fill kernel eliminated).
__global__ void prep_csq(const float* __restrict__ cb, const int* __restrict__ pad,
                         float* __restrict__ csqT,
                         int* __restrict__ cnt, int* __restrict__ list,
                         float* __restrict__ out_ids, float* __restrict__ out_q) {
    const int tid = threadIdx.x;
    const int idx = blockIdx.x * TPB_ + tid;     // < BT_ (exact grid)

    if (idx < V_ * G_) {
        const float4* r = (const float4*)(cb + (size_t)idx * D_);
        float s = 0.f;
#pragma unroll
        for (int i = 0; i < D_ / 4; ++i) {
            float4 c = r[i];
            s += c.x * c.x + c.y * c.y + c.z * c.z + c.w * c.w;
        }
        csqT[(idx & (G_ - 1)) * V_ + (idx >> 3)] = s;
    }

    __shared__ int s_cnt[8];          // [0..3] active per wave, [4..7] padded
    __shared__ int s_base, s_npl;
    __shared__ int s_plist[TPB_];     // block-local padded tokens
    const int lane = tid & 63, w = tid >> 6;
    const bool active = (pad[idx] == 0);
    u64 bal = __ballot(active);
    int na  = __popcll(bal);
    if (lane == 0) { s_cnt[w] = na; s_cnt[4 + w] = 64 - na; }
    __syncthreads();
    if (tid == 0) {
        int ta = s_cnt[0] + s_cnt[1] + s_cnt[2] + s_cnt[3];
        s_base = atomicAdd(cnt, ta);
        s_npl  = TPB_ - ta;
    }
    __syncthreads();
    int pre_a = 0, pre_p = 0;
    for (int i = 0; i < w; ++i) { pre_a += s_cnt[i]; pre_p += s_cnt[4 + i]; }
    const u64 mb = ((u64)1 << lane) - 1;
    if (active) list[s_base + pre_a + __popcll(bal & mb)] = idx;
    else        s_plist[pre_p + __popcll(~bal & mb)] = idx;
    __syncthreads();

    // coalesced zero-fill: one wave per padded token (2 KB contiguous)
    const int npl = s_npl;
    for (int i = w; i < npl; i += 4) {
        int tok = s_plist[i];
        float4 z = make_float4(0.f, 0.f, 0.f, 0.f);
        float4* q = (float4*)(out_q + (size_t)tok * (G_ * D_)) + lane * 2;
        q[0] = z;
        q[1] = z;
        if (lane < G_) out_ids[(size_t)tok * G_ + lane] = -1.0f;
    }
}

// Scan: block = 128 tok x 1024 cw; thread = 8 tok x 16 cw acc tile.
// 8 stage phases (32-d slices of 256-cw chunks); phase p+1's codebook data is
// prefetched into registers during phase p's compute (global latency hidden);
// barrier section only does 32 ds_writes. One generation: 512 active blocks
// at 2 blocks/CU. Numerics identical to R7/R8 (d ascending fmaf chain).
__global__ __launch_bounds__(TPB_, 2) void vq_scan(
    const float* __restrict__ inp,
    const float* __restrict__ cb,
    const float* __restrict__ csqT,
    const int* __restrict__ cnt,
    const int* __restrict__ list,
    float* __restrict__ out_ids,
    float* __restrict__ out_q,
    float* __restrict__ part) {

    __shared__ __align__(16) float XT[D_ * XROW_];   // [d][tok-staggered] 35 KB
    __shared__ __align__(16) float CT[DH_ * CWC_];   // [dl][cw]           32 KB
    __shared__ float csq_s[V_];                      //                     4 KB
    __shared__ u64 merge_s[4 * TOKS_];               //                     4 KB
    __shared__ u64 win_s[TOKS_];                     //                     1 KB

    const int nact = cnt[0];
    const int tile = blockIdx.x;
    if (tile * TOKS_ >= nact) return;          // uniform early-exit
    const int g   = blockIdx.y;
    const int tid = threadIdx.x;

    // ---- stage X^T (staggered) once: 2 threads per token ----
    {
        int tl = tid >> 1, dh = tid & 1;
        int p  = tile * TOKS_ + tl;
        int tok = list[p < nact ? p : 0];
        const float4* xr =
            (const float4*)(inp + (size_t)tok * (G_ * D_) + g * D_ + dh * 32);
        int base = xoff(tl >> 3) + (tl & 7);
#pragma unroll
        for (int k = 0; k < 8; ++k) {
            float4 v = xr[k];
            int d = dh * 32 + k * 4;
            XT[(d + 0) * XROW_ + base] = v.x;
            XT[(d + 1) * XROW_ + base] = v.y;
            XT[(d + 2) * XROW_ + base] = v.z;
            XT[(d + 3) * XROW_ + base] = v.w;
        }
    }
#pragma unroll
    for (int k = 0; k < 4; ++k)
        csq_s[k * 256 + tid] = csqT[g * V_ + k * 256 + tid];

    const int tg  = tid & 15;      // token group (8 tokens)
    const int cg  = tid >> 4;      // cw group (16 cw per chunk)
    const int xb0 = xoff(tg);

    float bestd[8];
    int   bestid[8];
#pragma unroll
    for (int i = 0; i < 8; ++i) { bestd[i] = FLT_MAX; bestid[i] = 0; }

    // prefetch phase 0: cw row (tid), d 0..31 -> 8 float4 in regs
    float4 pre[8];
    {
        const float4* src = (const float4*)(cb + ((size_t)tid * G_ + g) * D_);
#pragma unroll
        for (int k = 0; k < 8; ++k) pre[k] = src[k];
    }

    float acc[8][16];

    for (int p = 0; p < 8; ++p) {
        const int c = p >> 1, h = p & 1;
        __syncthreads();                       // CT readers of prev phase done
        // ---- write prefetched regs -> CT[dl][cw] (32 scalar stores, 2-way) ----
#pragma unroll
        for (int k = 0; k < 8; ++k) {
            int dl = k * 4;
            CT[(dl + 0) * CWC_ + tid] = pre[k].x;
            CT[(dl + 1) * CWC_ + tid] = pre[k].y;
            CT[(dl + 2) * CWC_ + tid] = pre[k].z;
            CT[(dl + 3) * CWC_ + tid] = pre[k].w;
        }
        if (p < 7) {                           // issue next phase's loads now;
            const int pn = p + 1;              // they complete during compute
            const int cn = pn >> 1, hn = pn & 1;
            const float4* src = (const float4*)(
                cb + ((size_t)(cn * CWC_ + tid) * G_ + g) * D_ + hn * DH_);
#pragma unroll
            for (int k = 0; k < 8; ++k) pre[k] = src[k];
        }
        __syncthreads();                       // CT ready

        if (h == 0) {
#pragma unroll
            for (int i = 0; i < 8; ++i)
#pragma unroll
                for (int j = 0; j < 16; ++j) acc[i][j] = 0.f;
        }

#pragma unroll 2
        for (int dl = 0; dl < DH_; ++dl) {
            const int d = h * DH_ + dl;
            float4 xa = *(const float4*)&XT[d * XROW_ + xb0];
            float4 xb = *(const float4*)&XT[d * XROW_ + xb0 + 4];
            float4 c0 = *(const float4*)&CT[dl * CWC_ + cg * 16];
            float4 c1 = *(const float4*)&CT[dl * CWC_ + cg * 16 + 4];
            float4 c2 = *(const float4*)&CT[dl * CWC_ + cg * 16 + 8];
            float4 c3 = *(const float4*)&CT[dl * CWC_ + cg * 16 + 12];
            float xs[8] = {xa.x, xa.y, xa.z, xa.w, xb.x, xb.y, xb.z, xb.w};
            float cs[16] = {c0.x, c0.y, c0.z, c0.w, c1.x, c1.y, c1.z, c1.w,
                            c2.x, c2.y, c2.z, c2.w, c3.x, c3.y, c3.z, c3.w};
#pragma unroll
            for (int i = 0; i < 8; ++i)
#pragma unroll
                for (int j = 0; j < 16; ++j)
                    acc[i][j] = fmaf(xs[i], cs[j], acc[i][j]);
        }

        if (h == 1) {                          // chunk complete: fold argmin
#pragma unroll
            for (int j = 0; j < 16; ++j) {
                float cq = csq_s[c * CWC_ + cg * 16 + j];
                int   v  = c * CWC_ + cg * 16 + j;
#pragma unroll
                for (int i = 0; i < 8; ++i) {
                    float dist = cq - 2.f * acc[i][j];
                    if (dist < bestd[i]) { bestd[i] = dist; bestid[i] = v; }
                }
            }
        }
    }

    // ---- cross-lane (cg) / cross-wave argmin merge ----
    const int lane = tid & 63;
    const int w    = tid >> 6;
    u64 pk[8];
#pragma unroll
    for (int i = 0; i < 8; ++i) {
        u32 u = __float_as_uint(bestd[i]);
        u = u ^ ((u >> 31) ? 0xFFFFFFFFu : 0x80000000u);   // sortable float
        pk[i] = ((u64)u << 32) | (u32)bestid[i];
    }
#pragma unroll
    for (int off = 16; off <= 32; off <<= 1) {             // reduce over cg
#pragma unroll
        for (int i = 0; i < 8; ++i) {
            u64 o = __shfl_xor(pk[i], off, 64);
            pk[i] = (o < pk[i]) ? o : pk[i];
        }
    }
    if (lane < 16) {
#pragma unroll
        for (int i = 0; i < 8; ++i) merge_s[w * TOKS_ + lane * 8 + i] = pk[i];
    }
    __syncthreads();
    if (tid < TOKS_) {
        u64 q = merge_s[tid];
#pragma unroll
        for (int ww = 1; ww < 4; ++ww) {
            u64 o = merge_s[ww * TOKS_ + tid];
            q = (o < q) ? o : q;
        }
        win_s[tid] = q;
    }
    __syncthreads();

    // ---- fused epilogue: ids, quantized, loss (2 threads per token) ----
    float l = 0.f;
    {
        int tl = tid >> 1, qv = tid & 1;
        int p  = tile * TOKS_ + tl;
        if (p < nact) {
            int tok = list[p];
            int id  = (int)(win_s[tl] & 0xFFFFFFFFull);
            const float4* cr = (const float4*)(cb + ((size_t)id * G_ + g) * D_) + qv * 8;
            const float4* xr = (const float4*)(inp + (size_t)tok * (G_ * D_) + g * D_) + qv * 8;
            float4* qo = (float4*)(out_q + (size_t)tok * (G_ * D_) + g * D_) + qv * 8;
#pragma unroll
            for (int k = 0; k < 8; ++k) {
                float4 cc = cr[k], xx = xr[k];
                float dx = cc.x - xx.x, dy = cc.y - xx.y;
                float dz = cc.z - xx.z, dw = cc.w - xx.w;
                l += dx * dx + dy * dy + dz * dz + dw * dw;
                qo[k] = cc;
            }
            if (qv == 0) out_ids[(size_t)tok * G_ + g] = (float)id;
        }
    }
#pragma unroll
    for (int off = 32; off > 0; off >>= 1) l += __shfl_down(l, off, 64);
    if (lane == 0) {
        int slot = ((blockIdx.y * gridDim.x + blockIdx.x) * 4 + w) & (NSLOT_ - 1);
        atomicAdd(&part[slot], l);
    }
}

__global__ void finalize_kernel(const float* __restrict__ part,
                                const int* __restrict__ cnt,
                                float* __restrict__ out_losses) {
    int lane = threadIdx.x;                    // one wave of 64
    float l = part[lane] + part[lane + 64];
#pragma unroll
    for (int off = 32; off > 0; off >>= 1) l += __shfl_down(l, off, 64);
    if (lane == 0) {
        float k = l / (float)cnt[0];
        out_losses[0] = k;        // kmeans_loss
        out_losses[1] = k;        // commitment_loss (numerically identical)
        out_losses[2] = 2.f * k;  // total (BETA=1)
    }
}

extern "C" void kernel_launch(void* const* d_in, const int* in_sizes, int n_in,
                              void* d_out, int out_size, void* d_ws, size_t ws_size,
                              hipStream_t stream) {
    const float* inp = (const float*)d_in[0];   // (8,2048,512) f32
    const int*   pad = (const int*)d_in[1];     // (8,2048) i32
    const float* cb  = (const float*)d_in[2];   // (1024,8,64) f32

    float* out   = (float*)d_out;
    float* o_ids = out;                              // B*T*G
    float* o_q   = out + (size_t)BT_ * G_;           // B*T*G*D
    float* o_ls  = o_q + (size_t)BT_ * G_ * D_;      // 3 scalars

    float* part  = (float*)d_ws;
    int*   cnt   = (int*)((char*)d_ws + 512);
    float* csqT  = (float*)((char*)d_ws + 1024);
    int*   list  = (int*)((char*)d_ws + 33792);

    hipMemsetAsync(d_ws, 0, 1024, stream);

    prep_csq<<<dim3(BT_ / TPB_), dim3(TPB_), 0, stream>>>(
        cb, pad, csqT, cnt, list, o_ids, o_q);

    dim3 grid(BT_ / TOKS_, G_);                // worst-case 128-token tiles x g
    vq_scan<<<grid, dim3(TPB_), 0, stream>>>(
        inp, cb, csqT, cnt, list, o_ids, o_q, part);

    finalize_kernel<<<1, dim3(64), 0, stream>>>(part, cnt, o_ls);
}